// Round 17
// baseline (1782.087 us; speedup 1.0000x reference)
//
#include <hip/hip_runtime.h>
#include <hip/hip_fp16.h>
#include <cstddef>
#include <cstdint>

#define U_DIM 256
#define G_DIM 1024          // 4*U
#define T_DIM 512
#define B_DIM 64
#define TC    32            // timesteps per chunk
#define LOG2TC 5
#define NCHUNK (T_DIM / TC) // 16
#define NSLOT  (NCHUNK + 2) // 18 pipeline slots
#define BHID   (B_DIM * U_DIM)
#define NPART  8            // final-proj j-range parts

// Weight residency split (proven round-9/11/16 structure)
#define NG_TOT 32
#define NG_REG 23
#define NG_LDS 9

#if __has_builtin(__builtin_amdgcn_global_load_lds)
#define HAS_GLL 1
#else
#define HAS_GLL 0
#endif

typedef _Float16 half2v __attribute__((ext_vector_type(2)));
typedef _Float16 f16x8  __attribute__((ext_vector_type(8)));
typedef float    f32x4  __attribute__((ext_vector_type(4)));

__device__ __forceinline__ float fsig(float x) {
    return 1.0f / (1.0f + __expf(-x));
}
__device__ __forceinline__ float ftanh(float x) {
    return 2.0f * fsig(2.0f * x) - 1.0f;
}

#define PIN4(v) asm("" : "+v"(v.x), "+v"(v.y), "+v"(v.z), "+v"(v.w))

// ---------------------------------------------------------------------------
// Pack U [256,1024] fp32 -> P: [32 groups][1024 cols] of uint4.
// P[g][n] holds f16(U[8g+0..8g+7][n]) packed 2-per-u32.
// (Also the MFMA B-fragment layout, verified rounds 7/10-16.)
// ---------------------------------------------------------------------------
__global__ __launch_bounds__(256)
void pack_w(const float* __restrict__ U, uint4* __restrict__ P)
{
    const int idx = blockIdx.x * 256 + threadIdx.x;   // 0..32767
    const int g = idx >> 10;
    const int n = idx & 1023;
    uint vals[4];
    #pragma unroll
    for (int j = 0; j < 4; ++j) {
        const int k = g * 8 + j * 2;
        const __half a = __float2half_rn(U[(size_t)k * G_DIM + n]);
        const __half b = __float2half_rn(U[(size_t)(k + 1) * G_DIM + n]);
        const unsigned short ua = __builtin_bit_cast(unsigned short, a);
        const unsigned short ub = __builtin_bit_cast(unsigned short, b);
        vals[j] = (uint)ua | ((uint)ub << 16);
    }
    P[idx] = make_uint4(vals[0], vals[1], vals[2], vals[3]);
}

// Pack x f32 -> f16, 8 elems/thread.
__global__ __launch_bounds__(256)
void pack_x(const float* __restrict__ x, __half* __restrict__ xh)
{
    const size_t i = ((size_t)blockIdx.x * 256 + threadIdx.x) * 8;
    const float4 a = *(const float4*)(x + i);
    const float4 b = *(const float4*)(x + i + 4);
    ushort4 o0, o1;
    o0.x = __builtin_bit_cast(unsigned short, __float2half_rn(a.x));
    o0.y = __builtin_bit_cast(unsigned short, __float2half_rn(a.y));
    o0.z = __builtin_bit_cast(unsigned short, __float2half_rn(a.z));
    o0.w = __builtin_bit_cast(unsigned short, __float2half_rn(a.w));
    o1.x = __builtin_bit_cast(unsigned short, __float2half_rn(b.x));
    o1.y = __builtin_bit_cast(unsigned short, __float2half_rn(b.y));
    o1.z = __builtin_bit_cast(unsigned short, __float2half_rn(b.z));
    o1.w = __builtin_bit_cast(unsigned short, __float2half_rn(b.w));
    *(ushort4*)(xh + i) = o0;
    *(ushort4*)(xh + i + 4) = o1;
}

// 8 MACs: acc += sum_j f16(h)[j] * f16(w)[j]
__device__ __forceinline__ float mac8(float acc, uint4 w, uint4 h)
{
#if __has_builtin(__builtin_amdgcn_fdot2)
    acc = __builtin_amdgcn_fdot2(__builtin_bit_cast(half2v, h.x),
                                 __builtin_bit_cast(half2v, w.x), acc, false);
    acc = __builtin_amdgcn_fdot2(__builtin_bit_cast(half2v, h.y),
                                 __builtin_bit_cast(half2v, w.y), acc, false);
    acc = __builtin_amdgcn_fdot2(__builtin_bit_cast(half2v, h.z),
                                 __builtin_bit_cast(half2v, w.z), acc, false);
    acc = __builtin_amdgcn_fdot2(__builtin_bit_cast(half2v, h.w),
                                 __builtin_bit_cast(half2v, w.w), acc, false);
#else
    const uint wv[4] = {w.x, w.y, w.z, w.w};
    const uint hv[4] = {h.x, h.y, h.z, h.w};
    #pragma unroll
    for (int j = 0; j < 4; ++j) {
        const __half2 wp = __builtin_bit_cast(__half2, wv[j]);
        const __half2 hp = __builtin_bit_cast(__half2, hv[j]);
        acc += __half2float(hp.x) * __half2float(wp.x);
        acc += __half2float(hp.y) * __half2float(wp.y);
    }
#endif
    return acc;
}

// xz buffer layout: [parity][layer][b][TC][G_DIM] f16
#define XZ_TILE ((size_t)TC * G_DIM)
#define XZ_AT(base, par, layer, b) \
    ((base) + ((((size_t)(par) * 3 + (layer)) * B_DIM + (b)) * XZ_TILE))

// ---------------------------------------------------------------------------
// Pipelined sequential LSTM with TAIL-FUSED next-slot xz GEMM.
// Grid = 192 blocks (3 layer-lanes x 64 rows) x 512 threads, 2 waves/SIMD.
// Step loop = round-16 proven structure (74.9 us incl preload).
// Tail (after step loop, pinned weights dead): 32x1024 MFMA gemm producing
// the xz tile needed NEXT slot:
//   layer0 -> xz[par+1][1][b] = h0(chunk s)  @ Wr + br
//   layer1 -> xz[par+1][2][b] = h1(chunk s-1)@ Wn + bn
//   layer2 -> xz[par+1][0][b] = xh(chunk s+1)@ Wr + br
// All cross-block reads are >=1 dispatch old (stream-ordered, no atomics).
// ---------------------------------------------------------------------------
__global__
__attribute__((amdgpu_flat_work_group_size(512, 512)))
__attribute__((amdgpu_waves_per_eu(2, 2)))
void lstm_pipe(int slot,
               const __half* __restrict__ xh,
               const uint4* __restrict__ Pr, const uint4* __restrict__ Pn,
               const uint4* __restrict__ PWr, const uint4* __restrict__ PWn,
               const float* __restrict__ br, const float* __restrict__ bn,
               __half* __restrict__ h0, __half* __restrict__ h1,
               __half* __restrict__ xzAll,
               float* __restrict__ hsAll, float* __restrict__ csAll)
{
    const int layer = blockIdx.x >> 6;
    const int b     = blockIdx.x & 63;
    const int c     = slot - layer;
    const bool do_lstm = (unsigned)c < (unsigned)NCHUNK;

    // tail chunk per layer: L0 -> s, L1 -> s-1, L2 -> s+1
    const int cc = (layer == 2) ? (slot + 1) : (slot - layer);
    const bool do_tail = (unsigned)cc < (unsigned)NCHUNK;
    if (!do_lstm && !do_tail) return;

    const int t = threadIdx.x;      // 0..511
    const int n0 = t;
    const int n1 = t + 512;

    __shared__ __align__(16) uint hq[U_DIM / 2];
    __shared__ float csh[U_DIM];
    __shared__ float zsh[G_DIM];
    __shared__ uint4 wlds[NG_LDS][G_DIM];          // 147 KB

    if (do_lstm) {
        const int t0 = c * TC;
        const uint4* __restrict__ P = (layer < 2) ? Pr : Pn;
        const __half* __restrict__ xzb = XZ_AT(xzAll, slot & 1, layer, b);
        const __half* __restrict__ resb =
            (layer == 1) ? (h0 + (size_t)(b * T_DIM + t0) * U_DIM) : nullptr;
        __half* __restrict__ outb =
            (layer == 0) ? (h0 + (size_t)(b * T_DIM + t0) * U_DIM)
          : (layer == 1) ? (h1 + (size_t)(b * T_DIM + t0) * U_DIM) : nullptr;
        float* __restrict__ hstate = hsAll + (size_t)layer * BHID + b * U_DIM;
        float* __restrict__ cstate = csAll + (size_t)layer * BHID + b * U_DIM;

        // ---- async wlds preload (round-16 proven) ----
#if HAS_GLL
        {
            const int wbase = t & ~63;
            #pragma unroll
            for (int g = 0; g < NG_LDS; ++g) {
                __builtin_amdgcn_global_load_lds(
                    (const __attribute__((address_space(1))) void*)
                        (P + (size_t)(NG_REG + g) * G_DIM + n0),
                    (__attribute__((address_space(3))) void*)&wlds[g][wbase],
                    16, 0, 0);
                __builtin_amdgcn_global_load_lds(
                    (const __attribute__((address_space(1))) void*)
                        (P + (size_t)(NG_REG + g) * G_DIM + n1),
                    (__attribute__((address_space(3))) void*)&wlds[g][512 + wbase],
                    16, 0, 0);
            }
        }
#else
        #pragma unroll
        for (int g = 0; g < NG_LDS; ++g) {
            wlds[g][n0] = P[(size_t)(NG_REG + g) * G_DIM + n0];
            wlds[g][n1] = P[(size_t)(NG_REG + g) * G_DIM + n1];
        }
#endif

        if (t < U_DIM) {
            float hv, cv;
            if (c == 0) { hv = 0.0f; cv = 0.0f; }
            else        { hv = hstate[t]; cv = cstate[t]; }
            csh[t] = cv;
            ((__half*)hq)[t] = __float2half_rn(hv);
        }

        uint4 wA[NG_REG], wB[NG_REG];
        #pragma unroll
        for (int g = 0; g < NG_REG; ++g) {
            wA[g] = P[(size_t)g * G_DIM + n0];
            wB[g] = P[(size_t)g * G_DIM + n1];
        }
        #pragma unroll
        for (int g = 0; g < NG_REG; ++g) { PIN4(wA[g]); PIN4(wB[g]); }

        __syncthreads();   // drains async wlds DMA + hq/csh init

        float cur0 = __half2float(xzb[n0]);
        float cur1 = __half2float(xzb[n1]);
        float resv = (resb && t < U_DIM) ? __half2float(resb[t]) : 0.0f;

        for (int tl = 0; tl < TC; ++tl) {
            float acc0 = cur0;
            float acc1 = cur1;

            const int tn = (tl + 1 < TC) ? (tl + 1) : (TC - 1);
            cur0 = __half2float(xzb[(size_t)tn * G_DIM + n0]);
            cur1 = __half2float(xzb[(size_t)tn * G_DIM + n1]);
            const float resn = (resb && t < U_DIM)
                             ? __half2float(resb[(size_t)tn * U_DIM + t]) : 0.0f;

            const uint4* __restrict__ hp = (const uint4*)hq;

            #pragma unroll
            for (int g = 0; g < NG_REG; ++g) {
                const uint4 h4 = hp[g];
                acc0 = mac8(acc0, wA[g], h4);
                acc1 = mac8(acc1, wB[g], h4);
            }
            #pragma unroll
            for (int g = 0; g < NG_LDS; ++g) {
                const uint4 h4 = hp[NG_REG + g];
                acc0 = mac8(acc0, wlds[g][n0], h4);
                acc1 = mac8(acc1, wlds[g][n1], h4);
            }

            zsh[n0] = fsig(acc0);
            zsh[n1] = (t < U_DIM) ? ftanh(acc1) : fsig(acc1);
            __syncthreads();

            if (t < U_DIM) {
                const float iv = zsh[t];
                const float fv = zsh[t + 256];
                const float gv = zsh[t + 512];
                const float ov = zsh[t + 768];
                const float cc2 = fv * csh[t] + iv * gv;
                const float hh = ov * ftanh(cc2);
                csh[t] = cc2;
                ((__half*)hq)[t] = __float2half_rn(hh);
                if (outb) outb[(size_t)tl * U_DIM + t] = __float2half_rn(hh + resv);
            }
            resv = resn;
            __syncthreads();   // final iteration: drains outb stores (vmcnt 0)
        }

        if (t < U_DIM) {
            hstate[t] = __half2float(((const __half*)hq)[t]);
            cstate[t] = csh[t];
        }
    }

    // ---- TAIL: next-slot xz GEMM (round-12-verified fragment path) ----
    if (do_tail) {
        const __half* __restrict__ asrc;
        const uint4*  __restrict__ PW2;
        const float*  __restrict__ bias2;
        __half* __restrict__ xzo;
        if (layer == 0) {
            asrc = h0;  PW2 = PWr; bias2 = br;
            xzo = XZ_AT(xzAll, (slot + 1) & 1, 1, b);
        } else if (layer == 1) {
            asrc = h1;  PW2 = PWn; bias2 = bn;
            xzo = XZ_AT(xzAll, (slot + 1) & 1, 2, b);
        } else {
            asrc = xh;  PW2 = PWr; bias2 = br;
            xzo = XZ_AT(xzAll, (slot + 1) & 1, 0, b);
        }
        const __half* arow0 =
            asrc + (size_t)(b * T_DIM + cc * TC + (t & 15)) * U_DIM + ((t & 63) >> 4) * 8;
        const __half* arow1 = arow0 + 16 * U_DIM;

        const int w = t >> 6;           // wave -> 128-col stripe
        const int l = t & 63;
        const int krow = l >> 4;

        #pragma unroll
        for (int ct = 0; ct < 8; ++ct) {
            const int col = w * 128 + ct * 16 + (l & 15);
            f32x4 acc0 = {0.f, 0.f, 0.f, 0.f};
            f32x4 acc1 = {0.f, 0.f, 0.f, 0.f};
            #pragma unroll
            for (int kt = 0; kt < 8; ++kt) {
                const uint4 bfrag = PW2[(size_t)(4 * kt + krow) * G_DIM + col];
                const uint4 a0 = *(const uint4*)(arow0 + kt * 32);
                const uint4 a1 = *(const uint4*)(arow1 + kt * 32);
                acc0 = __builtin_amdgcn_mfma_f32_16x16x32_f16(
                    __builtin_bit_cast(f16x8, a0), __builtin_bit_cast(f16x8, bfrag),
                    acc0, 0, 0, 0);
                acc1 = __builtin_amdgcn_mfma_f32_16x16x32_f16(
                    __builtin_bit_cast(f16x8, a1), __builtin_bit_cast(f16x8, bfrag),
                    acc1, 0, 0, 0);
            }
            const float bv = bias2[col];
            #pragma unroll
            for (int r = 0; r < 4; ++r) {
                const int row0 = 4 * krow + r;
                xzo[(size_t)row0 * G_DIM + col]        = __float2half_rn(acc0[r] + bv);
                xzo[(size_t)(row0 + 16) * G_DIM + col] = __float2half_rn(acc1[r] + bv);
            }
        }
    }
}

// ---------------------------------------------------------------------------
// MFMA input-projection GEMM (prologue only: seeds xz[0][0] = chunk 0 of
// layer 0). Round-11 version, grid (16, 32, 1), slot = 0.
// ---------------------------------------------------------------------------
__global__ __launch_bounds__(256)
void gemm3_mfma(int slot,
                const __half* __restrict__ xh,
                const __half* __restrict__ h0, const __half* __restrict__ h1,
                const uint4* __restrict__ PWr, const uint4* __restrict__ PWn,
                const float* __restrict__ br, const float* __restrict__ bn,
                __half* __restrict__ xzAll)
{
    const int z = blockIdx.z;
    const int c = slot - z;
    if ((unsigned)c >= (unsigned)NCHUNK) return;
    const int t0 = c * TC;

    const __half* __restrict__ A = (z == 0) ? xh : ((z == 1) ? h0 : h1);
    const uint4*  __restrict__ PW = (z < 2) ? PWr : PWn;
    const float*  __restrict__ bias = (z < 2) ? br : bn;
    __half* __restrict__ out = xzAll + (size_t)z * (B_DIM * TC * G_DIM);

    const int tid = threadIdx.x;
    const int w = tid >> 6;
    const int l = tid & 63;

    const int bm = blockIdx.y * 64;
    const int bn_ = blockIdx.x * 64;
    const int col = bn_ + w * 16 + (l & 15);
    const int krow = l >> 4;

    __shared__ __half ctile[64][68];

    const __half* arow[4];
    #pragma unroll
    for (int rt = 0; rt < 4; ++rt) {
        const int m = bm + rt * 16 + (l & 15);
        const int b = m >> LOG2TC;
        const int tl = m & (TC - 1);
        arow[rt] = A + (size_t)(b * T_DIM + t0 + tl) * U_DIM + krow * 8;
    }

    f32x4 acc[4] = {{0,0,0,0},{0,0,0,0},{0,0,0,0},{0,0,0,0}};

    #pragma unroll
    for (int kt = 0; kt < 8; ++kt) {
        const uint4 bfrag = PW[(size_t)(4 * kt + krow) * G_DIM + col];
        #pragma unroll
        for (int rt = 0; rt < 4; ++rt) {
            const uint4 afrag = *(const uint4*)(arow[rt] + kt * 32);
            acc[rt] = __builtin_amdgcn_mfma_f32_16x16x32_f16(
                __builtin_bit_cast(f16x8, afrag), __builtin_bit_cast(f16x8, bfrag),
                acc[rt], 0, 0, 0);
        }
    }

    const float bv = bias[col];
    const int ccol = w * 16 + (l & 15);
    #pragma unroll
    for (int rt = 0; rt < 4; ++rt) {
        #pragma unroll
        for (int r = 0; r < 4; ++r) {
            const int crow = rt * 16 + 4 * (l >> 4) + r;
            ctile[crow][ccol] = __float2half_rn(acc[rt][r] + bv);
        }
    }
    __syncthreads();

    {
        const int row = tid >> 2;
        const int quad = (tid & 3) * 16;
        const int m = bm + row;
        const int b = m >> LOG2TC;
        const int tl = m & (TC - 1);
        __half* dst = out + (size_t)(b * TC + tl) * G_DIM + bn_ + quad;
        const uint4 v0 = *(const uint4*)&ctile[row][quad];
        const uint4 v1 = *(const uint4*)&ctile[row][quad + 8];
        *(uint4*)dst = v0;
        *(uint4*)(dst + 8) = v1;
    }
}

// ---------------------------------------------------------------------------
// Final projection, stage A + B (unchanged).
// ---------------------------------------------------------------------------
__global__ __launch_bounds__(256)
void final_partial(const __half* __restrict__ h1, const float* __restrict__ h2,
                   const float* __restrict__ Wd, float* __restrict__ partials)
{
    const int b = blockIdx.x;
    const int p = blockIdx.y;
    const int tid = threadIdx.x;
    const int JTOT = T_DIM * U_DIM;          // 131072
    const int JPART = JTOT / NPART;          // 16384

    const __half* hb = h1 + (size_t)b * JTOT;
    const float* h2b = h2 + (size_t)b * U_DIM;

    float a0 = 0.f, a1 = 0.f, a2 = 0.f, a3 = 0.f;

    for (int j = p * JPART + tid * 8; j < (p + 1) * JPART; j += 256 * 8) {
        const uint4 hv = *(const uint4*)(hb + j);
        const int m = j & (U_DIM - 1);
        const float4 s0 = *(const float4*)(h2b + m);
        const float4 s1 = *(const float4*)(h2b + m + 4);
        float v[8];
        {
            const __half2 p0 = __builtin_bit_cast(__half2, hv.x);
            const __half2 p1 = __builtin_bit_cast(__half2, hv.y);
            const __half2 p2 = __builtin_bit_cast(__half2, hv.z);
            const __half2 p3 = __builtin_bit_cast(__half2, hv.w);
            v[0] = __half2float(p0.x) + s0.x;
            v[1] = __half2float(p0.y) + s0.y;
            v[2] = __half2float(p1.x) + s0.z;
            v[3] = __half2float(p1.y) + s0.w;
            v[4] = __half2float(p2.x) + s1.x;
            v[5] = __half2float(p2.y) + s1.y;
            v[6] = __half2float(p3.x) + s1.z;
            v[7] = __half2float(p3.y) + s1.w;
        }
        #pragma unroll
        for (int uu = 0; uu < 8; ++uu) {
            const float4 wv = *(const float4*)&Wd[(size_t)(j + uu) * 4];
            a0 += v[uu] * wv.x;
            a1 += v[uu] * wv.y;
            a2 += v[uu] * wv.z;
            a3 += v[uu] * wv.w;
        }
    }

    __shared__ float red[256][4];
    red[tid][0] = a0; red[tid][1] = a1; red[tid][2] = a2; red[tid][3] = a3;
    __syncthreads();
    for (int s = 128; s > 0; s >>= 1) {
        if (tid < s) {
            #pragma unroll
            for (int o = 0; o < 4; ++o) red[tid][o] += red[tid + s][o];
        }
        __syncthreads();
    }
    if (tid < 4) partials[((size_t)b * NPART + p) * 4 + tid] = red[0][tid];
}

__global__ __launch_bounds__(256)
void final_reduce(const float* __restrict__ partials, const float* __restrict__ bd,
                  float* __restrict__ y)
{
    const int tid = threadIdx.x;
    const int b = tid >> 2;
    const int o = tid & 3;
    float s = bd[o];
    #pragma unroll
    for (int p = 0; p < NPART; ++p)
        s += partials[((size_t)b * NPART + p) * 4 + o];
    y[b * 4 + o] = s;
}

// ---------------------------------------------------------------------------
extern "C" void kernel_launch(void* const* d_in, const int* in_sizes, int n_in,
                              void* d_out, int out_size, void* d_ws, size_t ws_size,
                              hipStream_t stream)
{
    (void)in_sizes; (void)n_in; (void)out_size; (void)ws_size;

    const float* x  = (const float*)d_in[0];
    const float* Wr = (const float*)d_in[1];
    const float* Ur = (const float*)d_in[2];
    const float* br = (const float*)d_in[3];
    const float* Wn = (const float*)d_in[4];
    const float* Un = (const float*)d_in[5];
    const float* bn = (const float*)d_in[6];
    const float* Wd = (const float*)d_in[7];
    const float* bd = (const float*)d_in[8];
    float* y = (float*)d_out;

    // ---- workspace layout ----
    char* wp = (char*)d_ws;
    uint4* Pr  = (uint4*)wp;  wp += (size_t)NG_TOT * G_DIM * 16;   // 512 KB
    uint4* Pn  = (uint4*)wp;  wp += (size_t)NG_TOT * G_DIM * 16;   // 512 KB
    uint4* PWr = (uint4*)wp;  wp += (size_t)NG_TOT * G_DIM * 16;   // 512 KB
    uint4* PWn = (uint4*)wp;  wp += (size_t)NG_TOT * G_DIM * 16;   // 512 KB
    float* hsAll = (float*)wp;      wp += (size_t)3 * BHID * 4;    // 196 KB
    float* csAll = (float*)wp;      wp += (size_t)3 * BHID * 4;    // 196 KB
    float* partials = (float*)wp;   wp += (size_t)B_DIM * NPART * 4 * 4;   // 8 KB
    wp = (char*)(((uintptr_t)wp + 255) & ~(uintptr_t)255);
    __half* xzAll = (__half*)wp; wp += (size_t)2 * 3 * B_DIM * TC * G_DIM * 2; // 25.2 MB
    __half* h0 = (__half*)wp;    wp += (size_t)B_DIM * T_DIM * U_DIM * 2;      // 16.8 MB
    __half* h1 = (__half*)wp;    wp += (size_t)B_DIM * T_DIM * U_DIM * 2;      // 16.8 MB
    __half* xh = (__half*)wp;    wp += (size_t)B_DIM * T_DIM * U_DIM * 2;      // 16.8 MB
    // total ~78 MB

    // ---- one-time packs ----
    pack_w<<<128, 256, 0, stream>>>(Ur, Pr);
    pack_w<<<128, 256, 0, stream>>>(Un, Pn);
    pack_w<<<128, 256, 0, stream>>>(Wr, PWr);
    pack_w<<<128, 256, 0, stream>>>(Wn, PWn);
    pack_x<<<(B_DIM * T_DIM * U_DIM) / (256 * 8), 256, 0, stream>>>(x, xh);

    // ---- prologue: seed xz[par=0][layer=0] with chunk 0 (z=0 only) ----
    {
        dim3 ggrid0(G_DIM / 64, (B_DIM * TC) / 64, 1);   // (16, 32, 1)
        gemm3_mfma<<<ggrid0, 256, 0, stream>>>(0, xh, h0, h1, PWr, PWn,
                                               br, bn, XZ_AT(xzAll, 0, 0, 0));
    }

    // ---- tail-fused wavefront: 18 stream-ordered dispatches, no atomics ----
    for (int slot = 0; slot < NSLOT; ++slot) {
        lstm_pipe<<<3 * B_DIM, 512, 0, stream>>>(slot, xh, Pr, Pn, PWr, PWn,
                                                 br, bn, h0, h1, xzAll,
                                                 hsAll, csAll);
    }

    // ---- final projection ----
    final_partial<<<dim3(B_DIM, NPART), 256, 0, stream>>>(h1, hsAll + 2 * BHID,
                                                          Wd, partials);
    final_reduce<<<1, 256, 0, stream>>>(partials, bd, y);
}

// Round 18
// 1635.093 us; speedup vs baseline: 1.0899x; 1.0899x over previous
//
#include <hip/hip_runtime.h>
#include <hip/hip_fp16.h>
#include <cstddef>
#include <cstdint>

#define U_DIM 256
#define G_DIM 1024          // 4*U
#define T_DIM 512
#define B_DIM 64
#define TC    32            // timesteps per chunk (proven best total: rounds 11/16)
#define LOG2TC 5
#define NCHUNK (T_DIM / TC) // 16
#define NSLOT  (NCHUNK + 2) // 18 pipeline slots
#define BHID   (B_DIM * U_DIM)
#define NPART  8            // final-proj j-range parts

// Weight residency split (proven round-9/11/16 structure)
#define NG_TOT 32
#define NG_REG 23
#define NG_LDS 9

#if __has_builtin(__builtin_amdgcn_global_load_lds)
#define HAS_GLL 1
#else
#define HAS_GLL 0
#endif

typedef _Float16 half2v __attribute__((ext_vector_type(2)));
typedef _Float16 f16x8  __attribute__((ext_vector_type(8)));
typedef float    f32x4  __attribute__((ext_vector_type(4)));

__device__ __forceinline__ float fsig(float x) {
    return 1.0f / (1.0f + __expf(-x));
}
__device__ __forceinline__ float ftanh(float x) {
    return 2.0f * fsig(2.0f * x) - 1.0f;
}

#define PIN4(v) asm("" : "+v"(v.x), "+v"(v.y), "+v"(v.z), "+v"(v.w))

// ---------------------------------------------------------------------------
// Pack U [256,1024] fp32 -> P: [32 groups][1024 cols] of uint4.
// P[g][n] holds f16(U[8g+0..8g+7][n]) packed 2-per-u32.
// (Also the MFMA B-fragment layout, verified rounds 7/10-17.)
// ---------------------------------------------------------------------------
__global__ __launch_bounds__(256)
void pack_w(const float* __restrict__ U, uint4* __restrict__ P)
{
    const int idx = blockIdx.x * 256 + threadIdx.x;   // 0..32767
    const int g = idx >> 10;
    const int n = idx & 1023;
    uint vals[4];
    #pragma unroll
    for (int j = 0; j < 4; ++j) {
        const int k = g * 8 + j * 2;
        const __half a = __float2half_rn(U[(size_t)k * G_DIM + n]);
        const __half b = __float2half_rn(U[(size_t)(k + 1) * G_DIM + n]);
        const unsigned short ua = __builtin_bit_cast(unsigned short, a);
        const unsigned short ub = __builtin_bit_cast(unsigned short, b);
        vals[j] = (uint)ua | ((uint)ub << 16);
    }
    P[idx] = make_uint4(vals[0], vals[1], vals[2], vals[3]);
}

// Pack x f32 -> f16, 8 elems/thread.
__global__ __launch_bounds__(256)
void pack_x(const float* __restrict__ x, __half* __restrict__ xh)
{
    const size_t i = ((size_t)blockIdx.x * 256 + threadIdx.x) * 8;
    const float4 a = *(const float4*)(x + i);
    const float4 b = *(const float4*)(x + i + 4);
    ushort4 o0, o1;
    o0.x = __builtin_bit_cast(unsigned short, __float2half_rn(a.x));
    o0.y = __builtin_bit_cast(unsigned short, __float2half_rn(a.y));
    o0.z = __builtin_bit_cast(unsigned short, __float2half_rn(a.z));
    o0.w = __builtin_bit_cast(unsigned short, __float2half_rn(a.w));
    o1.x = __builtin_bit_cast(unsigned short, __float2half_rn(b.x));
    o1.y = __builtin_bit_cast(unsigned short, __float2half_rn(b.y));
    o1.z = __builtin_bit_cast(unsigned short, __float2half_rn(b.z));
    o1.w = __builtin_bit_cast(unsigned short, __float2half_rn(b.w));
    *(ushort4*)(xh + i) = o0;
    *(ushort4*)(xh + i + 4) = o1;
}

// 8 MACs: acc += sum_j f16(h)[j] * f16(w)[j]
__device__ __forceinline__ float mac8(float acc, uint4 w, uint4 h)
{
#if __has_builtin(__builtin_amdgcn_fdot2)
    acc = __builtin_amdgcn_fdot2(__builtin_bit_cast(half2v, h.x),
                                 __builtin_bit_cast(half2v, w.x), acc, false);
    acc = __builtin_amdgcn_fdot2(__builtin_bit_cast(half2v, h.y),
                                 __builtin_bit_cast(half2v, w.y), acc, false);
    acc = __builtin_amdgcn_fdot2(__builtin_bit_cast(half2v, h.z),
                                 __builtin_bit_cast(half2v, w.z), acc, false);
    acc = __builtin_amdgcn_fdot2(__builtin_bit_cast(half2v, h.w),
                                 __builtin_bit_cast(half2v, w.w), acc, false);
#else
    const uint wv[4] = {w.x, w.y, w.z, w.w};
    const uint hv[4] = {h.x, h.y, h.z, h.w};
    #pragma unroll
    for (int j = 0; j < 4; ++j) {
        const __half2 wp = __builtin_bit_cast(__half2, wv[j]);
        const __half2 hp = __builtin_bit_cast(__half2, hv[j]);
        acc += __half2float(hp.x) * __half2float(wp.x);
        acc += __half2float(hp.y) * __half2float(wp.y);
    }
#endif
    return acc;
}

// ---------------------------------------------------------------------------
// Pipelined sequential LSTM (round-16 proven structure, 74.9 us/dispatch).
// Grid = 192 blocks (3 layer-lanes x 64 batch rows) x 512 threads, 2 waves/SIMD.
// Thread t owns gate-cols t and t+512. Weights: 23 groups reg-pinned,
// 9 groups in LDS preloaded via ASYNC global_load_lds issued BEFORE the
// 46 wreg register loads (DMA overlaps their L2 latency).
// ---------------------------------------------------------------------------
__global__
__attribute__((amdgpu_flat_work_group_size(512, 512)))
__attribute__((amdgpu_waves_per_eu(2, 2)))
void lstm_pipe(int slot,
               const __half* __restrict__ xzAll,
               const uint4* __restrict__ Pr, const uint4* __restrict__ Pn,
               __half* __restrict__ h0, __half* __restrict__ h1,
               float* __restrict__ hsAll, float* __restrict__ csAll)
{
    const int layer = blockIdx.x >> 6;
    const int b     = blockIdx.x & 63;
    const int c     = slot - layer;
    if ((unsigned)c >= (unsigned)NCHUNK) return;
    const int t0 = c * TC;

    const uint4* __restrict__ P = (layer < 2) ? Pr : Pn;
    const __half* __restrict__ xzb =
        xzAll + (size_t)layer * (B_DIM * TC * G_DIM) + (size_t)b * TC * G_DIM;
    const __half* __restrict__ resb =
        (layer == 1) ? (h0 + (size_t)(b * T_DIM + t0) * U_DIM) : nullptr;
    __half* __restrict__ outb =
        (layer == 0) ? (h0 + (size_t)(b * T_DIM + t0) * U_DIM)
      : (layer == 1) ? (h1 + (size_t)(b * T_DIM + t0) * U_DIM) : nullptr;
    float* __restrict__ hstate = hsAll + (size_t)layer * BHID + b * U_DIM;
    float* __restrict__ cstate = csAll + (size_t)layer * BHID + b * U_DIM;

    const int t = threadIdx.x;      // 0..511
    const int n0 = t;               // column A
    const int n1 = t + 512;         // column B

    __shared__ __align__(16) uint hq[U_DIM / 2];   // h packed f16 (512 B)
    __shared__ float csh[U_DIM];
    __shared__ float zsh[G_DIM];
    __shared__ uint4 wlds[NG_LDS][G_DIM];          // 147 KB

    // ---- phase A: ASYNC wlds preload (issued first; drains at syncthreads) ----
#if HAS_GLL
    {
        const int wbase = t & ~63;   // wave-uniform LDS slot base (lane x 16B dest)
        #pragma unroll
        for (int g = 0; g < NG_LDS; ++g) {
            __builtin_amdgcn_global_load_lds(
                (const __attribute__((address_space(1))) void*)
                    (P + (size_t)(NG_REG + g) * G_DIM + n0),
                (__attribute__((address_space(3))) void*)&wlds[g][wbase],
                16, 0, 0);
            __builtin_amdgcn_global_load_lds(
                (const __attribute__((address_space(1))) void*)
                    (P + (size_t)(NG_REG + g) * G_DIM + n1),
                (__attribute__((address_space(3))) void*)&wlds[g][512 + wbase],
                16, 0, 0);
        }
    }
#else
    #pragma unroll
    for (int g = 0; g < NG_LDS; ++g) {
        wlds[g][n0] = P[(size_t)(NG_REG + g) * G_DIM + n0];
        wlds[g][n1] = P[(size_t)(NG_REG + g) * G_DIM + n1];
    }
#endif

    // ---- carry state (issued early, overlaps with wreg loads) ----
    if (t < U_DIM) {
        float hv, cv;
        if (c == 0) { hv = 0.0f; cv = 0.0f; }
        else        { hv = hstate[t]; cv = cstate[t]; }
        csh[t] = cv;
        ((__half*)hq)[t] = __float2half_rn(hv);
    }

    // ---- wreg preload (46 x uint4 from L2; overlapped with the DMA above) ----
    uint4 wA[NG_REG], wB[NG_REG];
    #pragma unroll
    for (int g = 0; g < NG_REG; ++g) {
        wA[g] = P[(size_t)g * G_DIM + n0];
        wB[g] = P[(size_t)g * G_DIM + n1];
    }
    #pragma unroll
    for (int g = 0; g < NG_REG; ++g) { PIN4(wA[g]); PIN4(wB[g]); }

    __syncthreads();   // drains async wlds DMA + hq/csh init

    float cur0 = __half2float(xzb[n0]);
    float cur1 = __half2float(xzb[n1]);
    float resv = (resb && t < U_DIM) ? __half2float(resb[t]) : 0.0f;

    for (int tl = 0; tl < TC; ++tl) {
        float acc0 = cur0;
        float acc1 = cur1;

        const int tn = (tl + 1 < TC) ? (tl + 1) : (TC - 1);
        cur0 = __half2float(xzb[(size_t)tn * G_DIM + n0]);
        cur1 = __half2float(xzb[(size_t)tn * G_DIM + n1]);
        const float resn = (resb && t < U_DIM)
                         ? __half2float(resb[(size_t)tn * U_DIM + t]) : 0.0f;

        const uint4* __restrict__ hp = (const uint4*)hq;

        #pragma unroll
        for (int g = 0; g < NG_REG; ++g) {
            const uint4 h4 = hp[g];
            acc0 = mac8(acc0, wA[g], h4);
            acc1 = mac8(acc1, wB[g], h4);
        }
        #pragma unroll
        for (int g = 0; g < NG_LDS; ++g) {
            const uint4 h4 = hp[NG_REG + g];
            acc0 = mac8(acc0, wlds[g][n0], h4);
            acc1 = mac8(acc1, wlds[g][n1], h4);
        }

        zsh[n0] = fsig(acc0);
        zsh[n1] = (t < U_DIM) ? ftanh(acc1) : fsig(acc1);
        __syncthreads();

        if (t < U_DIM) {
            const float iv = zsh[t];
            const float fv = zsh[t + 256];
            const float gv = zsh[t + 512];
            const float ov = zsh[t + 768];
            const float cc = fv * csh[t] + iv * gv;
            const float hh = ov * ftanh(cc);
            csh[t] = cc;
            ((__half*)hq)[t] = __float2half_rn(hh);
            if (outb) outb[(size_t)tl * U_DIM + t] = __float2half_rn(hh + resv);
        }
        resv = resn;
        __syncthreads();
    }

    if (t < U_DIM) {
        hstate[t] = __half2float(((const __half*)hq)[t]);
        cstate[t] = csh[t];
    }
}

// ---------------------------------------------------------------------------
// MFMA input-projection GEMM (round-11 version: LDS-staged coalesced epilogue).
// Grid (16 Nblk, (B*TC)/64 Mblk, 3 lanes) x 256 threads.
// ---------------------------------------------------------------------------
__global__ __launch_bounds__(256)
void gemm3_mfma(int slot,
                const __half* __restrict__ xh,
                const __half* __restrict__ h0, const __half* __restrict__ h1,
                const uint4* __restrict__ PWr, const uint4* __restrict__ PWn,
                const float* __restrict__ br, const float* __restrict__ bn,
                __half* __restrict__ xzAll)
{
    const int z = blockIdx.z;
    const int c = slot - z;
    if ((unsigned)c >= (unsigned)NCHUNK) return;
    const int t0 = c * TC;

    const __half* __restrict__ A = (z == 0) ? xh : ((z == 1) ? h0 : h1);
    const uint4*  __restrict__ PW = (z < 2) ? PWr : PWn;
    const float*  __restrict__ bias = (z < 2) ? br : bn;
    __half* __restrict__ out = xzAll + (size_t)z * (B_DIM * TC * G_DIM);

    const int tid = threadIdx.x;
    const int w = tid >> 6;
    const int l = tid & 63;

    const int bm = blockIdx.y * 64;
    const int bn_ = blockIdx.x * 64;
    const int col = bn_ + w * 16 + (l & 15);
    const int krow = l >> 4;

    __shared__ __half ctile[64][68];

    const __half* arow[4];
    #pragma unroll
    for (int rt = 0; rt < 4; ++rt) {
        const int m = bm + rt * 16 + (l & 15);
        const int b = m >> LOG2TC;
        const int tl = m & (TC - 1);
        arow[rt] = A + (size_t)(b * T_DIM + t0 + tl) * U_DIM + krow * 8;
    }

    f32x4 acc[4] = {{0,0,0,0},{0,0,0,0},{0,0,0,0},{0,0,0,0}};

    #pragma unroll
    for (int kt = 0; kt < 8; ++kt) {
        const uint4 bfrag = PW[(size_t)(4 * kt + krow) * G_DIM + col];
        #pragma unroll
        for (int rt = 0; rt < 4; ++rt) {
            const uint4 afrag = *(const uint4*)(arow[rt] + kt * 32);
            acc[rt] = __builtin_amdgcn_mfma_f32_16x16x32_f16(
                __builtin_bit_cast(f16x8, afrag), __builtin_bit_cast(f16x8, bfrag),
                acc[rt], 0, 0, 0);
        }
    }

    const float bv = bias[col];
    const int ccol = w * 16 + (l & 15);
    #pragma unroll
    for (int rt = 0; rt < 4; ++rt) {
        #pragma unroll
        for (int r = 0; r < 4; ++r) {
            const int crow = rt * 16 + 4 * (l >> 4) + r;
            ctile[crow][ccol] = __float2half_rn(acc[rt][r] + bv);
        }
    }
    __syncthreads();

    {
        const int row = tid >> 2;
        const int quad = (tid & 3) * 16;
        const int m = bm + row;
        const int b = m >> LOG2TC;
        const int tl = m & (TC - 1);
        __half* dst = out + (size_t)(b * TC + tl) * G_DIM + bn_ + quad;
        const uint4 v0 = *(const uint4*)&ctile[row][quad];
        const uint4 v1 = *(const uint4*)&ctile[row][quad + 8];
        *(uint4*)dst = v0;
        *(uint4*)(dst + 8) = v1;
    }
}

// ---------------------------------------------------------------------------
// Final projection, stage A + B (unchanged).
// ---------------------------------------------------------------------------
__global__ __launch_bounds__(256)
void final_partial(const __half* __restrict__ h1, const float* __restrict__ h2,
                   const float* __restrict__ Wd, float* __restrict__ partials)
{
    const int b = blockIdx.x;
    const int p = blockIdx.y;
    const int tid = threadIdx.x;
    const int JTOT = T_DIM * U_DIM;          // 131072
    const int JPART = JTOT / NPART;          // 16384

    const __half* hb = h1 + (size_t)b * JTOT;
    const float* h2b = h2 + (size_t)b * U_DIM;

    float a0 = 0.f, a1 = 0.f, a2 = 0.f, a3 = 0.f;

    for (int j = p * JPART + tid * 8; j < (p + 1) * JPART; j += 256 * 8) {
        const uint4 hv = *(const uint4*)(hb + j);
        const int m = j & (U_DIM - 1);
        const float4 s0 = *(const float4*)(h2b + m);
        const float4 s1 = *(const float4*)(h2b + m + 4);
        float v[8];
        {
            const __half2 p0 = __builtin_bit_cast(__half2, hv.x);
            const __half2 p1 = __builtin_bit_cast(__half2, hv.y);
            const __half2 p2 = __builtin_bit_cast(__half2, hv.z);
            const __half2 p3 = __builtin_bit_cast(__half2, hv.w);
            v[0] = __half2float(p0.x) + s0.x;
            v[1] = __half2float(p0.y) + s0.y;
            v[2] = __half2float(p1.x) + s0.z;
            v[3] = __half2float(p1.y) + s0.w;
            v[4] = __half2float(p2.x) + s1.x;
            v[5] = __half2float(p2.y) + s1.y;
            v[6] = __half2float(p3.x) + s1.z;
            v[7] = __half2float(p3.y) + s1.w;
        }
        #pragma unroll
        for (int uu = 0; uu < 8; ++uu) {
            const float4 wv = *(const float4*)&Wd[(size_t)(j + uu) * 4];
            a0 += v[uu] * wv.x;
            a1 += v[uu] * wv.y;
            a2 += v[uu] * wv.z;
            a3 += v[uu] * wv.w;
        }
    }

    __shared__ float red[256][4];
    red[tid][0] = a0; red[tid][1] = a1; red[tid][2] = a2; red[tid][3] = a3;
    __syncthreads();
    for (int s = 128; s > 0; s >>= 1) {
        if (tid < s) {
            #pragma unroll
            for (int o = 0; o < 4; ++o) red[tid][o] += red[tid + s][o];
        }
        __syncthreads();
    }
    if (tid < 4) partials[((size_t)b * NPART + p) * 4 + tid] = red[0][tid];
}

__global__ __launch_bounds__(256)
void final_reduce(const float* __restrict__ partials, const float* __restrict__ bd,
                  float* __restrict__ y)
{
    const int tid = threadIdx.x;
    const int b = tid >> 2;
    const int o = tid & 3;
    float s = bd[o];
    #pragma unroll
    for (int p = 0; p < NPART; ++p)
        s += partials[((size_t)b * NPART + p) * 4 + o];
    y[b * 4 + o] = s;
}

// ---------------------------------------------------------------------------
extern "C" void kernel_launch(void* const* d_in, const int* in_sizes, int n_in,
                              void* d_out, int out_size, void* d_ws, size_t ws_size,
                              hipStream_t stream)
{
    (void)in_sizes; (void)n_in; (void)out_size; (void)ws_size;

    const float* x  = (const float*)d_in[0];
    const float* Wr = (const float*)d_in[1];
    const float* Ur = (const float*)d_in[2];
    const float* br = (const float*)d_in[3];
    const float* Wn = (const float*)d_in[4];
    const float* Un = (const float*)d_in[5];
    const float* bn = (const float*)d_in[6];
    const float* Wd = (const float*)d_in[7];
    const float* bd = (const float*)d_in[8];
    float* y = (float*)d_out;

    // ---- workspace layout ----
    char* wp = (char*)d_ws;
    uint4* Pr  = (uint4*)wp;  wp += (size_t)NG_TOT * G_DIM * 16;   // 512 KB
    uint4* Pn  = (uint4*)wp;  wp += (size_t)NG_TOT * G_DIM * 16;   // 512 KB
    uint4* PWr = (uint4*)wp;  wp += (size_t)NG_TOT * G_DIM * 16;   // 512 KB
    uint4* PWn = (uint4*)wp;  wp += (size_t)NG_TOT * G_DIM * 16;   // 512 KB
    float* hsAll = (float*)wp;      wp += (size_t)3 * BHID * 4;    // 196 KB
    float* csAll = (float*)wp;      wp += (size_t)3 * BHID * 4;    // 196 KB
    float* partials = (float*)wp;   wp += (size_t)B_DIM * NPART * 4 * 4;   // 8 KB
    wp = (char*)(((uintptr_t)wp + 255) & ~(uintptr_t)255);
    __half* xzAll = (__half*)wp; wp += (size_t)3 * B_DIM * TC * G_DIM * 2; // 12.6 MB
    __half* h0 = (__half*)wp;    wp += (size_t)B_DIM * T_DIM * U_DIM * 2;  // 16.8 MB
    __half* h1 = (__half*)wp;    wp += (size_t)B_DIM * T_DIM * U_DIM * 2;  // 16.8 MB
    __half* xh = (__half*)wp;    wp += (size_t)B_DIM * T_DIM * U_DIM * 2;  // 16.8 MB
    // total ~66 MB

    // ---- one-time packs ----
    pack_w<<<128, 256, 0, stream>>>(Ur, Pr);
    pack_w<<<128, 256, 0, stream>>>(Un, Pn);
    pack_w<<<128, 256, 0, stream>>>(Wr, PWr);
    pack_w<<<128, 256, 0, stream>>>(Wn, PWn);
    pack_x<<<(B_DIM * T_DIM * U_DIM) / (256 * 8), 256, 0, stream>>>(x, xh);

    // ---- software-pipelined layer x chunk wavefront (stream-ordered) ----
    dim3 ggrid(G_DIM / 64, (B_DIM * TC) / 64, 3);   // (16, 32, 3)
    for (int slot = 0; slot < NSLOT; ++slot) {
        gemm3_mfma<<<ggrid, 256, 0, stream>>>(slot, xh, h0, h1, PWr, PWn,
                                              br, bn, xzAll);
        lstm_pipe<<<3 * B_DIM, 512, 0, stream>>>(slot, xzAll, Pr, Pn,
                                                 h0, h1, hsAll, csAll);
    }

    // ---- final projection ----
    final_partial<<<dim3(B_DIM, NPART), 256, 0, stream>>>(h1, hsAll + 2 * BHID,
                                                          Wd, partials);
    final_reduce<<<1, 256, 0, stream>>>(partials, bd, y);
}